// Round 4
// baseline (6419.318 us; speedup 1.0000x reference)
//
#include <hip/hip_runtime.h>

// NequIP-style layer, f32.
// Fast path (~62.8MB ws): CSR edge-permutation -> gather_fused
//   (8 nodes/block, wave-per-node; Wm3^T staged swizzled in 64KB LDS;
//    radial MLP via readlane-broadcast; no atomics) -> node_post.
// Fallback path (61.4MB ws): atomic edge_kernel (round-1, known-good).

#define NN 20000
#define NE 320000

__device__ __forceinline__ float swishf(float x) {
  float t = __expf(-fabsf(x));
  float r = 1.0f / (1.0f + t);
  float sig = (x >= 0.0f) ? r : t * r;
  return x * sig;
}

__device__ __forceinline__ float rlane(float v, int k) {
  return __uint_as_float(__builtin_amdgcn_readlane(__float_as_uint(v), k));
}

__device__ __forceinline__ void ld8(float d[8], const float* p) {
  float4 a0 = *(const float4*)p;
  float4 a1 = *(const float4*)(p + 4);
  d[0]=a0.x; d[1]=a0.y; d[2]=a0.z; d[3]=a0.w;
  d[4]=a1.x; d[5]=a1.y; d[6]=a1.z; d[7]=a1.w;
}

__device__ __forceinline__ void fma8(float (&acc)[8], const float* p, float w) {
  float4 a0 = *(const float4*)p;
  float4 a1 = *(const float4*)(p + 4);
  acc[0] = fmaf(a0.x, w, acc[0]); acc[1] = fmaf(a0.y, w, acc[1]);
  acc[2] = fmaf(a0.z, w, acc[2]); acc[3] = fmaf(a0.w, w, acc[3]);
  acc[4] = fmaf(a1.x, w, acc[4]); acc[5] = fmaf(a1.y, w, acc[5]);
  acc[6] = fmaf(a1.z, w, acc[6]); acc[7] = fmaf(a1.w, w, acc[7]);
}

// ---------------- CSR build ----------------
__global__ __launch_bounds__(256) void hist_kernel(const int* __restrict__ rcv,
                                                   int* __restrict__ counts) {
  int e = blockIdx.x * 256 + threadIdx.x;
  atomicAdd(&counts[rcv[e]], 1);
}

__global__ __launch_bounds__(1024) void scan_kernel(const int* __restrict__ counts,
                                                    int* __restrict__ offsets,
                                                    int* __restrict__ cursor) {
  __shared__ int part[1024];
  const int t = threadIdx.x;
  const int base = t * 20;
  int loc[20];
  int s = 0;
  #pragma unroll
  for (int j = 0; j < 20; ++j) {
    int idx = base + j;
    int c = (idx < NN) ? counts[idx] : 0;
    loc[j] = s;
    s += c;
  }
  part[t] = s;
  __syncthreads();
  for (int d = 1; d < 1024; d <<= 1) {
    int v = (t >= d) ? part[t - d] : 0;
    __syncthreads();
    part[t] += v;
    __syncthreads();
  }
  int excl = (t > 0) ? part[t - 1] : 0;
  #pragma unroll
  for (int j = 0; j < 20; ++j) {
    int idx = base + j;
    if (idx < NN) {
      int o = excl + loc[j];
      offsets[idx] = o;
      cursor[idx] = o;
    }
  }
  if (t == 1023) offsets[NN] = part[1023];
}

__global__ __launch_bounds__(256) void scatter_kernel(
    const int* __restrict__ rcv, int* __restrict__ cursor,
    int* __restrict__ csr_edge) {
  int e = blockIdx.x * 256 + threadIdx.x;
  int r = rcv[e];
  int pos = atomicAdd(&cursor[r], 1);
  csr_edge[pos] = e;
}

// ---------------- kernel A: y = [x0@Wl0, x1@Wl1] * nl ----------------
__global__ __launch_bounds__(256) void node_prep(
    const float* __restrict__ feats, const float* __restrict__ Wl0,
    const float* __restrict__ Wl1, float* __restrict__ y)
{
  __shared__ __align__(16) float sX[4 * 256];
  const int t = threadIdx.x;
  const int n0 = blockIdx.x * 4;
  #pragma unroll
  for (int nb = 0; nb < 4; ++nb)
    sX[nb * 256 + t] = feats[(size_t)(n0 + nb) * 256 + t];
  __syncthreads();

  float acc[4] = {0.f, 0.f, 0.f, 0.f};
  if (t < 64) {
    const int v = t;
    for (int u = 0; u < 64; ++u) {
      float w = Wl0[u * 64 + v];
      acc[0] = fmaf(sX[0 * 256 + u], w, acc[0]);
      acc[1] = fmaf(sX[1 * 256 + u], w, acc[1]);
      acc[2] = fmaf(sX[2 * 256 + u], w, acc[2]);
      acc[3] = fmaf(sX[3 * 256 + u], w, acc[3]);
    }
  } else {
    const int i = t - 64;
    const int v = i / 3;
    const int m = i - v * 3;
    for (int u = 0; u < 64; ++u) {
      float w = Wl1[u * 64 + v];
      int xi = 64 + u * 3 + m;
      acc[0] = fmaf(sX[0 * 256 + xi], w, acc[0]);
      acc[1] = fmaf(sX[1 * 256 + xi], w, acc[1]);
      acc[2] = fmaf(sX[2 * 256 + xi], w, acc[2]);
      acc[3] = fmaf(sX[3 * 256 + xi], w, acc[3]);
    }
  }
  #pragma unroll
  for (int nb = 0; nb < 4; ++nb)
    y[(size_t)(n0 + nb) * 256 + t] = acc[nb] * 0.125f;   // nl = 1/sqrt(64)
}

// ---------------- fused gather v2 ----------------
// 8 nodes/block (512 thr), wave-per-node, batch-4 edges.
// Wm3^T in LDS, swizzled for conflict-free ds_read_b128:
//   logical (row r, k): phys float idx = r*64 + ((g ^ (r&15))<<2) + kk,
//   g=k>>2, kk=k&3.  Read: lane l, p -> row p*64+l (r&15 == l&15).
__global__ __launch_bounds__(512, 4) void gather_fused(
    const float* __restrict__ y, const int* __restrict__ csr_edge,
    const int* __restrict__ snd, const float* __restrict__ esh,
    const float* __restrict__ emb, const float* __restrict__ Wm1,
    const float* __restrict__ Wm2, const float* __restrict__ Wm3,
    const int* __restrict__ offsets, float* __restrict__ agg)
{
  __shared__ __align__(16) float sW3[64 * 256];   // 64KB
  const int t = threadIdx.x;

  // stage Wm3 (k-major [64][256]) -> sW3 transposed+swizzled
  #pragma unroll 4
  for (int i = 0; i < 32; ++i) {
    int idx = i * 512 + t;          // 0..16383
    int k = idx >> 8;               // 0..63
    int c = idx & 255;              // output dim 0..255
    float v = Wm3[idx];
    int kg = k >> 2, kk = k & 3;
    sW3[c * 64 + (((kg ^ (c & 15)) & 15) << 2) + kk] = v;
  }
  __syncthreads();

  const int l = t & 63;
  const int wv = t >> 6;
  const int n = blockIdx.x * 8 + wv;
  const int row0 = offsets[n];
  const int row1 = offsets[n + 1];

  // hoist Wm1 column l (8 persistent regs)
  float wm1r[8];
  #pragma unroll
  for (int j = 0; j < 8; ++j) wm1r[j] = Wm1[j * 64 + l];
  const float* Wm2l = Wm2 + l;

  float s0 = 0.f, s1 = 0.f;
  float v0x = 0.f, v0y = 0.f, v0z = 0.f;
  float v1x = 0.f, v1y = 0.f, v1z = 0.f;

  const int swz = ((l & 15) << 2);   // row-dependent part of the XOR swizzle

  for (int i = row0; i < row1; i += 4) {
    const int nb = row1 - i;

    int   sn[4];
    float4 sh[4];
    float h1[4];
    #pragma unroll
    for (int b = 0; b < 4; ++b) {
      int idx = (b < nb) ? (i + b) : i;      // duplicate edge 0 if inactive
      int e = csr_edge[idx];
      sn[b] = snd[e];
      float4 s = *(const float4*)(esh + (size_t)e * 4);
      if (b >= nb) s = make_float4(0.f, 0.f, 0.f, 0.f);  // every TP term has sh
      sh[b] = s;
      float em8[8];
      ld8(em8, emb + (size_t)e * 8);
      float a = 0.f;
      #pragma unroll
      for (int j = 0; j < 8; ++j) a = fmaf(em8[j], wm1r[j], a);
      h1[b] = swishf(a * 0.35355339059327373f);    // /sqrt(8)
    }

    // ---- h2[l] = swish( (sum_k h1[k]*Wm2[k][l]) / 8 ) ----
    float h2[4] = {0.f, 0.f, 0.f, 0.f};
    #pragma unroll
    for (int k = 0; k < 64; ++k) {
      float wv2 = Wm2l[k * 64];
      h2[0] = fmaf(rlane(h1[0], k), wv2, h2[0]);
      h2[1] = fmaf(rlane(h1[1], k), wv2, h2[1]);
      h2[2] = fmaf(rlane(h1[2], k), wv2, h2[2]);
      h2[3] = fmaf(rlane(h1[3], k), wv2, h2[3]);
    }
    #pragma unroll
    for (int b = 0; b < 4; ++b) h2[b] = swishf(h2[b] * 0.125f);

    // ---- w[p*64+l] = sum_k h2[k]*Wm3[k][p*64+l] via LDS b128 reads ----
    float w0[4] = {0,0,0,0}, w1a[4] = {0,0,0,0}, w2a[4] = {0,0,0,0}, w3a[4] = {0,0,0,0};
    #pragma unroll
    for (int g = 0; g < 16; ++g) {
      int sbase = l * 64 + (((g << 2) ^ swz) & 63);   // ((g^(l&15))<<2)
      float4 m0 = *(const float4*)&sW3[sbase];
      float4 m1 = *(const float4*)&sW3[sbase + 4096];
      float4 m2 = *(const float4*)&sW3[sbase + 8192];
      float4 m3 = *(const float4*)&sW3[sbase + 12288];
      #pragma unroll
      for (int kk = 0; kk < 4; ++kk) {
        const int k = 4 * g + kk;
        #pragma unroll
        for (int b = 0; b < 4; ++b) {
          float bc = rlane(h2[b], k);
          w0[b] = fmaf(bc, (&m0.x)[kk], w0[b]);
          w1a[b] = fmaf(bc, (&m1.x)[kk], w1a[b]);
          w2a[b] = fmaf(bc, (&m2.x)[kk], w2a[b]);
          w3a[b] = fmaf(bc, (&m3.x)[kk], w3a[b]);
        }
      }
    }

    // ---- tensor product + accumulate ----
    #pragma unroll
    for (int b = 0; b < 4; ++b) {
      const float* yr = y + (size_t)sn[b] * 256;
      float e0 = yr[l];
      float ex = yr[64 + 3 * l], ey = yr[65 + 3 * l], ez = yr[66 + 3 * l];
      float4 s = sh[b];
      s0 = fmaf(w0[b] * e0, s.x, s0);
      s1 = fmaf(w3a[b], fmaf(ex, s.y, fmaf(ey, s.z, ez * s.w)), s1);
      float t2 = w1a[b] * e0;
      v0x = fmaf(t2, s.y, v0x); v0y = fmaf(t2, s.z, v0y); v0z = fmaf(t2, s.w, v0z);
      float t3 = w2a[b] * s.x;
      v1x = fmaf(t3, ex, v1x); v1y = fmaf(t3, ey, v1y); v1z = fmaf(t3, ez, v1z);
    }
  }

  const float SCL = 0.0078125f;                          // (1/8 w-scale) / 16
  const float C4  = 0.125f / (16.0f * 1.7320508075688772f);
  float* ar = agg + (size_t)n * 512;
  ar[l]       = s0 * SCL;
  ar[64 + l]  = s1 * C4;
  ar[128 + 3 * l]     = v0x * SCL;
  ar[128 + 3 * l + 1] = v0y * SCL;
  ar[128 + 3 * l + 2] = v0z * SCL;
  ar[320 + 3 * l]     = v1x * SCL;
  ar[320 + 3 * l + 1] = v1y * SCL;
  ar[320 + 3 * l + 2] = v1z * SCL;
}

// GEMV helper (fallback path)
__device__ __forceinline__ void wgemv(float (&wa)[64], const float* __restrict__ Wm3,
                                      const float* h2col, int p)
{
  #pragma unroll
  for (int v = 0; v < 64; ++v) wa[v] = 0.f;
  #pragma unroll 2
  for (int k = 0; k < 64; ++k) {
    float h2k = h2col[k * 256];
    const float* wrow = Wm3 + k * 256 + p * 64;
    #pragma unroll
    for (int v = 0; v < 64; ++v) wa[v] = fmaf(h2k, wrow[v], wa[v]);
  }
}

// ---------------- fallback: atomic edge kernel (round-1, known-good) ----------------
__global__ __launch_bounds__(256) void edge_kernel(
    const float* __restrict__ y, const float* __restrict__ edge_sh,
    const int* __restrict__ senders, const int* __restrict__ receivers,
    const float* __restrict__ emb, const float* __restrict__ Wm1,
    const float* __restrict__ Wm2, const float* __restrict__ Wm3,
    float* __restrict__ agg)
{
  __shared__ float h2s[64 * 256];
  const int tid = threadIdx.x;
  const int e = blockIdx.x * 256 + tid;
  const int s = senders[e];
  const int r = receivers[e];
  const float4 shv = *(const float4*)(edge_sh + (size_t)e * 4);
  float e8[8];
  ld8(e8, emb + (size_t)e * 8);

  float h2a[64];
  #pragma unroll
  for (int v = 0; v < 64; ++v) h2a[v] = 0.f;
  #pragma unroll 2
  for (int k = 0; k < 64; ++k) {
    float a = 0.f;
    #pragma unroll
    for (int j = 0; j < 8; ++j) a = fmaf(e8[j], Wm1[j * 64 + k], a);
    float h1k = swishf(a * 0.35355339059327373f);
    const float* wrow = Wm2 + k * 64;
    #pragma unroll
    for (int v = 0; v < 64; ++v) h2a[v] = fmaf(h1k, wrow[v], h2a[v]);
  }
  #pragma unroll
  for (int v = 0; v < 64; ++v)
    h2s[v * 256 + tid] = swishf(h2a[v] * 0.125f);

  const float* yrow = y + (size_t)s * 256;
  float* aggr = agg + (size_t)r * 512;
  const float SCL = 0.0078125f;
  const float c0  = shv.x * SCL;
  const float c1x = shv.y * SCL, c1y = shv.z * SCL, c1z = shv.w * SCL;
  const float c4  = 0.125f / (16.0f * 1.7320508075688772f);

  float wa[64];

  wgemv(wa, Wm3, h2s + tid, 0);
  #pragma unroll
  for (int uc = 0; uc < 8; ++uc) {
    float ev[8];
    ld8(ev, yrow + uc * 8);
    #pragma unroll
    for (int j = 0; j < 8; ++j) {
      int u = uc * 8 + j;
      atomicAdd(&aggr[u], wa[u] * ev[j] * c0);
    }
  }
  wgemv(wa, Wm3, h2s + tid, 1);
  #pragma unroll
  for (int uc = 0; uc < 8; ++uc) {
    float ev[8];
    ld8(ev, yrow + uc * 8);
    #pragma unroll
    for (int j = 0; j < 8; ++j) {
      int u = uc * 8 + j;
      float tt = wa[u] * ev[j];
      atomicAdd(&aggr[128 + 3 * u    ], tt * c1x);
      atomicAdd(&aggr[128 + 3 * u + 1], tt * c1y);
      atomicAdd(&aggr[128 + 3 * u + 2], tt * c1z);
    }
  }
  wgemv(wa, Wm3, h2s + tid, 2);
  #pragma unroll
  for (int uc = 0; uc < 8; ++uc) {
    float ev[24];
    ld8(ev,      yrow + 64 + uc * 24);
    ld8(ev + 8,  yrow + 64 + uc * 24 + 8);
    ld8(ev + 16, yrow + 64 + uc * 24 + 16);
    #pragma unroll
    for (int j = 0; j < 8; ++j) {
      int u = uc * 8 + j;
      float tt = wa[u] * c0;
      atomicAdd(&aggr[320 + 3 * u    ], tt * ev[3 * j    ]);
      atomicAdd(&aggr[320 + 3 * u + 1], tt * ev[3 * j + 1]);
      atomicAdd(&aggr[320 + 3 * u + 2], tt * ev[3 * j + 2]);
    }
  }
  wgemv(wa, Wm3, h2s + tid, 3);
  #pragma unroll
  for (int uc = 0; uc < 8; ++uc) {
    float ev[24];
    ld8(ev,      yrow + 64 + uc * 24);
    ld8(ev + 8,  yrow + 64 + uc * 24 + 8);
    ld8(ev + 16, yrow + 64 + uc * 24 + 16);
    #pragma unroll
    for (int j = 0; j < 8; ++j) {
      int u = uc * 8 + j;
      float d = ev[3*j]*shv.y + ev[3*j+1]*shv.z + ev[3*j+2]*shv.w;
      atomicAdd(&aggr[64 + u], wa[u] * d * c4);
    }
  }
}

// ---------------- kernel C: node post ----------------
__global__ __launch_bounds__(256) void node_post(
    const float* __restrict__ feats, const float* __restrict__ attrs,
    const float* __restrict__ agg, const float* __restrict__ W2s,
    const float* __restrict__ W2v, const float* __restrict__ Wr_s,
    const float* __restrict__ Wr_v, float* __restrict__ out)
{
  __shared__ __align__(16) float sA[320 * 8];
  __shared__ __align__(16) float sX0[64 * 8];
  __shared__ __align__(16) float sX1[192 * 8];
  __shared__ __align__(16) float sAt[5 * 8];
  __shared__ __align__(16) float sAggS[128 * 8];
  __shared__ __align__(16) float sAggV[384 * 8];
  __shared__ __align__(16) float sZs[8 * 128];
  __shared__ __align__(16) float sZv[8 * 192];

  const int t = threadIdx.x;
  const int n0 = blockIdx.x * 8;
  const float nr = 0.05590169943749474f;
  const float n2 = 0.08838834764831845f;

  #pragma unroll
  for (int nb = 0; nb < 8; ++nb) {
    float v = feats[(size_t)(n0 + nb) * 256 + t];
    if (t < 64) sX0[t * 8 + nb] = v;
    else        sX1[(t - 64) * 8 + nb] = v;
  }
  if (t < 40) {
    int nb = t & 7, s = t >> 3;
    sAt[s * 8 + nb] = attrs[(size_t)(n0 + nb) * 5 + s] * nr;
  }
  #pragma unroll
  for (int i = 0; i < 16; ++i) {
    int idx = i * 256 + t;
    int nb = idx >> 9;
    int c = idx & 511;
    float v = agg[(size_t)(n0 + nb) * 512 + c] * n2;
    if (c < 128) sAggS[c * 8 + nb] = v;
    else         sAggV[(c - 128) * 8 + nb] = v;
  }
  __syncthreads();

  #pragma unroll
  for (int i = 0; i < 10; ++i) {
    int idx = i * 256 + t;
    int nb = idx & 7;
    int us = idx >> 3;
    int u = us / 5;
    int s = us - u * 5;
    sA[us * 8 + nb] = sX0[u * 8 + nb] * sAt[s * 8 + nb];
  }
  __syncthreads();

  float av[8][3];

  if (t < 128) {
    const int v = t;
    float acc[8];
    #pragma unroll
    for (int nb = 0; nb < 8; ++nb) acc[nb] = 0.f;
    for (int us = 0; us < 320; ++us)
      fma8(acc, &sA[us * 8], Wr_s[us * 128 + v]);
    for (int c = 0; c < 128; ++c)
      fma8(acc, &sAggS[c * 8], W2s[c * 128 + v]);
    #pragma unroll
    for (int nb = 0; nb < 8; ++nb) sZs[nb * 128 + v] = acc[nb];
  } else {
    const int tv = t - 128;
    const int v = tv & 63;
    const int half = tv >> 6;
    #pragma unroll
    for (int nb = 0; nb < 8; ++nb)
      #pragma unroll
      for (int m = 0; m < 3; ++m) av[nb][m] = 0.f;

    const int u0 = half * 32;
    for (int u = u0; u < u0 + 32; ++u) {
      float xr0[8], xr1[8], xr2[8];
      ld8(xr0, &sX1[(u * 3 + 0) * 8]);
      ld8(xr1, &sX1[(u * 3 + 1) * 8]);
      ld8(xr2, &sX1[(u * 3 + 2) * 8]);
      #pragma unroll
      for (int s = 0; s < 5; ++s) {
        float w = Wr_v[(u * 5 + s) * 64 + v];
        float at[8];
        ld8(at, &sAt[s * 8]);
        #pragma unroll
        for (int nb = 0; nb < 8; ++nb) {
          float tt = at[nb] * w;
          av[nb][0] = fmaf(xr0[nb], tt, av[nb][0]);
          av[nb][1] = fmaf(xr1[nb], tt, av[nb][1]);
          av[nb][2] = fmaf(xr2[nb], tt, av[nb][2]);
        }
      }
    }
    const int c0 = half * 64;
    for (int c = c0; c < c0 + 64; ++c) {
      float w = W2v[c * 64 + v];
      float g0[8], g1[8], g2[8];
      ld8(g0, &sAggV[(c * 3 + 0) * 8]);
      ld8(g1, &sAggV[(c * 3 + 1) * 8]);
      ld8(g2, &sAggV[(c * 3 + 2) * 8]);
      #pragma unroll
      for (int nb = 0; nb < 8; ++nb) {
        av[nb][0] = fmaf(g0[nb], w, av[nb][0]);
        av[nb][1] = fmaf(g1[nb], w, av[nb][1]);
        av[nb][2] = fmaf(g2[nb], w, av[nb][2]);
      }
    }
    if (half == 0) {
      #pragma unroll
      for (int nb = 0; nb < 8; ++nb)
        #pragma unroll
        for (int m = 0; m < 3; ++m)
          sZv[nb * 192 + v * 3 + m] = av[nb][m];
    }
  }
  __syncthreads();
  if (t >= 192) {
    const int v = (t - 128) & 63;
    #pragma unroll
    for (int nb = 0; nb < 8; ++nb)
      #pragma unroll
      for (int m = 0; m < 3; ++m)
        sZv[nb * 192 + v * 3 + m] += av[nb][m];
  }
  __syncthreads();

  const int i = t - 64;
  const int ug = (t >= 64) ? (i / 3) : 0;
  #pragma unroll
  for (int nb = 0; nb < 8; ++nb) {
    float val;
    if (t < 64) {
      val = swishf(sZs[nb * 128 + t]);
    } else {
      float gate = swishf(sZs[nb * 128 + 64 + ug]);
      val = gate * sZv[nb * 192 + i];
    }
    out[(size_t)(n0 + nb) * 256 + t] = val;
  }
}

extern "C" void kernel_launch(void* const* d_in, const int* in_sizes, int n_in,
                              void* d_out, int out_size, void* d_ws, size_t ws_size,
                              hipStream_t stream)
{
  const float* feats = (const float*)d_in[0];
  const float* attrs = (const float*)d_in[1];
  const float* esh   = (const float*)d_in[2];
  const int*   snd   = (const int*)d_in[3];
  const int*   rcv   = (const int*)d_in[4];
  const float* emb   = (const float*)d_in[5];
  const float* Wl0   = (const float*)d_in[6];
  const float* Wl1   = (const float*)d_in[7];
  const float* Wm1   = (const float*)d_in[8];
  const float* Wm2   = (const float*)d_in[9];
  const float* Wm3   = (const float*)d_in[10];
  const float* W2s   = (const float*)d_in[11];
  const float* W2v   = (const float*)d_in[12];
  const float* Wr_s  = (const float*)d_in[13];
  const float* Wr_v  = (const float*)d_in[14];
  float* out = (float*)d_out;

  float* y   = (float*)d_ws;                     // NN*256 f32
  float* agg = y + (size_t)NN * 256;             // NN*512 f32
  // CSR-build transients aliased into agg (agg written only by gather_fused):
  int* counts = (int*)agg;
  int* cursor = counts + NN;
  int* csr_edge = (int*)(agg + (size_t)NN * 512);   // NE ints
  int* offsets  = csr_edge + NE;                    // NN+1 ints
  size_t need = (size_t)((char*)(offsets + NN + 1) - (char*)d_ws);

  if (ws_size >= need) {
    hipMemsetAsync(counts, 0, (size_t)NN * sizeof(int), stream);
    hist_kernel<<<NE / 256, 256, 0, stream>>>(rcv, counts);
    scan_kernel<<<1, 1024, 0, stream>>>(counts, offsets, cursor);
    scatter_kernel<<<NE / 256, 256, 0, stream>>>(rcv, cursor, csr_edge);
    node_prep<<<NN / 4, 256, 0, stream>>>(feats, Wl0, Wl1, y);
    gather_fused<<<NN / 8, 512, 0, stream>>>(y, csr_edge, snd, esh, emb,
                                             Wm1, Wm2, Wm3, offsets, agg);
    node_post<<<NN / 8, 256, 0, stream>>>(feats, attrs, agg, W2s, W2v, Wr_s, Wr_v, out);
  } else {
    hipMemsetAsync(agg, 0, (size_t)NN * 512 * sizeof(float), stream);
    node_prep<<<NN / 4, 256, 0, stream>>>(feats, Wl0, Wl1, y);
    edge_kernel<<<NE / 256, 256, 0, stream>>>(y, esh, snd, rcv, emb, Wm1, Wm2, Wm3, agg);
    node_post<<<NN / 8, 256, 0, stream>>>(feats, attrs, agg, W2s, W2v, Wr_s, Wr_v, out);
  }
}

// Round 5
// 5460.680 us; speedup vs baseline: 1.1756x; 1.1756x over previous
//
#include <hip/hip_runtime.h>

// NequIP-style layer, f32.
// Fast path (~62.8MB ws): CSR edge-permutation -> gather_fused
//   (8 nodes/block wave-per-node, batch-2 edges; Wm3 staged swizzled in 64KB
//    LDS; readlane-broadcast GEMVs; no atomics, no spills) -> node_post.
// Fallback path (61.4MB ws): atomic edge_kernel (round-1, known-good).

#define NN 20000
#define NE 320000

__device__ __forceinline__ float swishf(float x) {
  float t = __expf(-fabsf(x));
  float r = 1.0f / (1.0f + t);
  float sig = (x >= 0.0f) ? r : t * r;
  return x * sig;
}

__device__ __forceinline__ float rlane(float v, int k) {
  return __uint_as_float(__builtin_amdgcn_readlane(__float_as_uint(v), k));
}

__device__ __forceinline__ void ld8(float d[8], const float* p) {
  float4 a0 = *(const float4*)p;
  float4 a1 = *(const float4*)(p + 4);
  d[0]=a0.x; d[1]=a0.y; d[2]=a0.z; d[3]=a0.w;
  d[4]=a1.x; d[5]=a1.y; d[6]=a1.z; d[7]=a1.w;
}

__device__ __forceinline__ void fma8(float (&acc)[8], const float* p, float w) {
  float4 a0 = *(const float4*)p;
  float4 a1 = *(const float4*)(p + 4);
  acc[0] = fmaf(a0.x, w, acc[0]); acc[1] = fmaf(a0.y, w, acc[1]);
  acc[2] = fmaf(a0.z, w, acc[2]); acc[3] = fmaf(a0.w, w, acc[3]);
  acc[4] = fmaf(a1.x, w, acc[4]); acc[5] = fmaf(a1.y, w, acc[5]);
  acc[6] = fmaf(a1.z, w, acc[6]); acc[7] = fmaf(a1.w, w, acc[7]);
}

// ---------------- CSR build ----------------
__global__ __launch_bounds__(256) void hist_kernel(const int* __restrict__ rcv,
                                                   int* __restrict__ counts) {
  int e = blockIdx.x * 256 + threadIdx.x;
  atomicAdd(&counts[rcv[e]], 1);
}

__global__ __launch_bounds__(1024) void scan_kernel(const int* __restrict__ counts,
                                                    int* __restrict__ offsets,
                                                    int* __restrict__ cursor) {
  __shared__ int part[1024];
  const int t = threadIdx.x;
  const int base = t * 20;
  int loc[20];
  int s = 0;
  #pragma unroll
  for (int j = 0; j < 20; ++j) {
    int idx = base + j;
    int c = (idx < NN) ? counts[idx] : 0;
    loc[j] = s;
    s += c;
  }
  part[t] = s;
  __syncthreads();
  for (int d = 1; d < 1024; d <<= 1) {
    int v = (t >= d) ? part[t - d] : 0;
    __syncthreads();
    part[t] += v;
    __syncthreads();
  }
  int excl = (t > 0) ? part[t - 1] : 0;
  #pragma unroll
  for (int j = 0; j < 20; ++j) {
    int idx = base + j;
    if (idx < NN) {
      int o = excl + loc[j];
      offsets[idx] = o;
      cursor[idx] = o;
    }
  }
  if (t == 1023) offsets[NN] = part[1023];
}

__global__ __launch_bounds__(256) void scatter_kernel(
    const int* __restrict__ rcv, int* __restrict__ cursor,
    int* __restrict__ csr_edge) {
  int e = blockIdx.x * 256 + threadIdx.x;
  int r = rcv[e];
  int pos = atomicAdd(&cursor[r], 1);
  csr_edge[pos] = e;
}

// ---------------- kernel A: y = [x0@Wl0, x1@Wl1] * nl ----------------
__global__ __launch_bounds__(256) void node_prep(
    const float* __restrict__ feats, const float* __restrict__ Wl0,
    const float* __restrict__ Wl1, float* __restrict__ y)
{
  __shared__ __align__(16) float sX[4 * 256];
  const int t = threadIdx.x;
  const int n0 = blockIdx.x * 4;
  #pragma unroll
  for (int nb = 0; nb < 4; ++nb)
    sX[nb * 256 + t] = feats[(size_t)(n0 + nb) * 256 + t];
  __syncthreads();

  float acc[4] = {0.f, 0.f, 0.f, 0.f};
  if (t < 64) {
    const int v = t;
    for (int u = 0; u < 64; ++u) {
      float w = Wl0[u * 64 + v];
      acc[0] = fmaf(sX[0 * 256 + u], w, acc[0]);
      acc[1] = fmaf(sX[1 * 256 + u], w, acc[1]);
      acc[2] = fmaf(sX[2 * 256 + u], w, acc[2]);
      acc[3] = fmaf(sX[3 * 256 + u], w, acc[3]);
    }
  } else {
    const int i = t - 64;
    const int v = i / 3;
    const int m = i - v * 3;
    for (int u = 0; u < 64; ++u) {
      float w = Wl1[u * 64 + v];
      int xi = 64 + u * 3 + m;
      acc[0] = fmaf(sX[0 * 256 + xi], w, acc[0]);
      acc[1] = fmaf(sX[1 * 256 + xi], w, acc[1]);
      acc[2] = fmaf(sX[2 * 256 + xi], w, acc[2]);
      acc[3] = fmaf(sX[3 * 256 + xi], w, acc[3]);
    }
  }
  #pragma unroll
  for (int nb = 0; nb < 4; ++nb)
    y[(size_t)(n0 + nb) * 256 + t] = acc[nb] * 0.125f;   // nl = 1/sqrt(64)
}

// ---------------- fused gather v3 ----------------
// 8 nodes/block (512 thr), wave-per-node, batch-2 edges (spill-proof).
// Wm3^T in LDS, swizzled for conflict-free ds_read_b128:
//   logical (row r, k): phys float idx = r*64 + ((g ^ (r&15))<<2) + kk.
__global__ __launch_bounds__(512, 2) void gather_fused(
    const float* __restrict__ y, const int* __restrict__ csr_edge,
    const int* __restrict__ snd, const float* __restrict__ esh,
    const float* __restrict__ emb, const float* __restrict__ Wm1,
    const float* __restrict__ Wm2, const float* __restrict__ Wm3,
    const int* __restrict__ offsets, float* __restrict__ agg)
{
  __shared__ __align__(16) float sW3[64 * 256];   // 64KB
  const int t = threadIdx.x;

  // stage Wm3 (k-major [64][256]) -> sW3 transposed+swizzled
  #pragma unroll 4
  for (int i = 0; i < 32; ++i) {
    int idx = i * 512 + t;          // 0..16383
    int k = idx >> 8;               // 0..63
    int c = idx & 255;              // output dim 0..255
    float v = Wm3[idx];
    int kg = k >> 2, kk = k & 3;
    sW3[c * 64 + (((kg ^ (c & 15)) & 15) << 2) + kk] = v;
  }
  __syncthreads();

  const int l = t & 63;
  const int wv = t >> 6;
  const int n = blockIdx.x * 8 + wv;
  const int row0 = offsets[n];
  const int row1 = offsets[n + 1];

  // hoist Wm1 column l (8 persistent regs)
  float wm1r[8];
  #pragma unroll
  for (int j = 0; j < 8; ++j) wm1r[j] = Wm1[j * 64 + l];
  const float* Wm2l = Wm2 + l;

  float s0 = 0.f, s1 = 0.f;
  float v0x = 0.f, v0y = 0.f, v0z = 0.f;
  float v1x = 0.f, v1y = 0.f, v1z = 0.f;

  const int swz = ((l & 15) << 2);   // row-dependent part of the XOR swizzle

  for (int i = row0; i < row1; i += 2) {
    const int nb = row1 - i;

    int   sn[2];
    float4 sh[2];
    float h1[2];
    #pragma unroll
    for (int b = 0; b < 2; ++b) {
      int idx = (b < nb) ? (i + b) : i;      // duplicate edge 0 if inactive
      int e = csr_edge[idx];
      sn[b] = snd[e];
      float4 s = *(const float4*)(esh + (size_t)e * 4);
      if (b >= nb) s = make_float4(0.f, 0.f, 0.f, 0.f);  // every TP term has sh
      sh[b] = s;
      float em8[8];
      ld8(em8, emb + (size_t)e * 8);
      float a = 0.f;
      #pragma unroll
      for (int j = 0; j < 8; ++j) a = fmaf(em8[j], wm1r[j], a);
      h1[b] = swishf(a * 0.35355339059327373f);    // /sqrt(8)
    }

    // ---- h2[l] = swish( (sum_k h1[k]*Wm2[k][l]) / 8 ) ----
    float h2[2] = {0.f, 0.f};
    #pragma unroll
    for (int k = 0; k < 64; ++k) {
      float wv2 = Wm2l[k * 64];
      h2[0] = fmaf(rlane(h1[0], k), wv2, h2[0]);
      h2[1] = fmaf(rlane(h1[1], k), wv2, h2[1]);
    }
    h2[0] = swishf(h2[0] * 0.125f);
    h2[1] = swishf(h2[1] * 0.125f);

    // ---- w[p*64+l] = sum_k h2[k]*Wm3[k][p*64+l] via LDS b128 reads ----
    float w0[2] = {0,0}, w1a[2] = {0,0}, w2a[2] = {0,0}, w3a[2] = {0,0};
    #pragma unroll
    for (int g = 0; g < 16; ++g) {
      int sbase = l * 64 + (((g << 2) ^ swz) & 63);   // ((g^(l&15))<<2)
      float4 m0 = *(const float4*)&sW3[sbase];
      float4 m1 = *(const float4*)&sW3[sbase + 4096];
      float4 m2 = *(const float4*)&sW3[sbase + 8192];
      float4 m3 = *(const float4*)&sW3[sbase + 12288];
      #pragma unroll
      for (int kk = 0; kk < 4; ++kk) {
        const int k = 4 * g + kk;
        #pragma unroll
        for (int b = 0; b < 2; ++b) {
          float bc = rlane(h2[b], k);
          w0[b]  = fmaf(bc, (&m0.x)[kk], w0[b]);
          w1a[b] = fmaf(bc, (&m1.x)[kk], w1a[b]);
          w2a[b] = fmaf(bc, (&m2.x)[kk], w2a[b]);
          w3a[b] = fmaf(bc, (&m3.x)[kk], w3a[b]);
        }
      }
    }

    // ---- tensor product + accumulate ----
    #pragma unroll
    for (int b = 0; b < 2; ++b) {
      const float* yr = y + (size_t)sn[b] * 256;
      float e0 = yr[l];
      float ex = yr[64 + 3 * l], ey = yr[65 + 3 * l], ez = yr[66 + 3 * l];
      float4 s = sh[b];
      s0 = fmaf(w0[b] * e0, s.x, s0);
      s1 = fmaf(w3a[b], fmaf(ex, s.y, fmaf(ey, s.z, ez * s.w)), s1);
      float t2 = w1a[b] * e0;
      v0x = fmaf(t2, s.y, v0x); v0y = fmaf(t2, s.z, v0y); v0z = fmaf(t2, s.w, v0z);
      float t3 = w2a[b] * s.x;
      v1x = fmaf(t3, ex, v1x); v1y = fmaf(t3, ey, v1y); v1z = fmaf(t3, ez, v1z);
    }
  }

  const float SCL = 0.0078125f;                          // (1/8 w-scale) / 16
  const float C4  = 0.125f / (16.0f * 1.7320508075688772f);
  float* ar = agg + (size_t)n * 512;
  ar[l]       = s0 * SCL;
  ar[64 + l]  = s1 * C4;
  ar[128 + 3 * l]     = v0x * SCL;
  ar[128 + 3 * l + 1] = v0y * SCL;
  ar[128 + 3 * l + 2] = v0z * SCL;
  ar[320 + 3 * l]     = v1x * SCL;
  ar[320 + 3 * l + 1] = v1y * SCL;
  ar[320 + 3 * l + 2] = v1z * SCL;
}

// GEMV helper (fallback path)
__device__ __forceinline__ void wgemv(float (&wa)[64], const float* __restrict__ Wm3,
                                      const float* h2col, int p)
{
  #pragma unroll
  for (int v = 0; v < 64; ++v) wa[v] = 0.f;
  #pragma unroll 2
  for (int k = 0; k < 64; ++k) {
    float h2k = h2col[k * 256];
    const float* wrow = Wm3 + k * 256 + p * 64;
    #pragma unroll
    for (int v = 0; v < 64; ++v) wa[v] = fmaf(h2k, wrow[v], wa[v]);
  }
}

// ---------------- fallback: atomic edge kernel (round-1, known-good) ----------------
__global__ __launch_bounds__(256) void edge_kernel(
    const float* __restrict__ y, const float* __restrict__ edge_sh,
    const int* __restrict__ senders, const int* __restrict__ receivers,
    const float* __restrict__ emb, const float* __restrict__ Wm1,
    const float* __restrict__ Wm2, const float* __restrict__ Wm3,
    float* __restrict__ agg)
{
  __shared__ float h2s[64 * 256];
  const int tid = threadIdx.x;
  const int e = blockIdx.x * 256 + tid;
  const int s = senders[e];
  const int r = receivers[e];
  const float4 shv = *(const float4*)(edge_sh + (size_t)e * 4);
  float e8[8];
  ld8(e8, emb + (size_t)e * 8);

  float h2a[64];
  #pragma unroll
  for (int v = 0; v < 64; ++v) h2a[v] = 0.f;
  #pragma unroll 2
  for (int k = 0; k < 64; ++k) {
    float a = 0.f;
    #pragma unroll
    for (int j = 0; j < 8; ++j) a = fmaf(e8[j], Wm1[j * 64 + k], a);
    float h1k = swishf(a * 0.35355339059327373f);
    const float* wrow = Wm2 + k * 64;
    #pragma unroll
    for (int v = 0; v < 64; ++v) h2a[v] = fmaf(h1k, wrow[v], h2a[v]);
  }
  #pragma unroll
  for (int v = 0; v < 64; ++v)
    h2s[v * 256 + tid] = swishf(h2a[v] * 0.125f);

  const float* yrow = y + (size_t)s * 256;
  float* aggr = agg + (size_t)r * 512;
  const float SCL = 0.0078125f;
  const float c0  = shv.x * SCL;
  const float c1x = shv.y * SCL, c1y = shv.z * SCL, c1z = shv.w * SCL;
  const float c4  = 0.125f / (16.0f * 1.7320508075688772f);

  float wa[64];

  wgemv(wa, Wm3, h2s + tid, 0);
  #pragma unroll
  for (int uc = 0; uc < 8; ++uc) {
    float ev[8];
    ld8(ev, yrow + uc * 8);
    #pragma unroll
    for (int j = 0; j < 8; ++j) {
      int u = uc * 8 + j;
      atomicAdd(&aggr[u], wa[u] * ev[j] * c0);
    }
  }
  wgemv(wa, Wm3, h2s + tid, 1);
  #pragma unroll
  for (int uc = 0; uc < 8; ++uc) {
    float ev[8];
    ld8(ev, yrow + uc * 8);
    #pragma unroll
    for (int j = 0; j < 8; ++j) {
      int u = uc * 8 + j;
      float tt = wa[u] * ev[j];
      atomicAdd(&aggr[128 + 3 * u    ], tt * c1x);
      atomicAdd(&aggr[128 + 3 * u + 1], tt * c1y);
      atomicAdd(&aggr[128 + 3 * u + 2], tt * c1z);
    }
  }
  wgemv(wa, Wm3, h2s + tid, 2);
  #pragma unroll
  for (int uc = 0; uc < 8; ++uc) {
    float ev[24];
    ld8(ev,      yrow + 64 + uc * 24);
    ld8(ev + 8,  yrow + 64 + uc * 24 + 8);
    ld8(ev + 16, yrow + 64 + uc * 24 + 16);
    #pragma unroll
    for (int j = 0; j < 8; ++j) {
      int u = uc * 8 + j;
      float tt = wa[u] * c0;
      atomicAdd(&aggr[320 + 3 * u    ], tt * ev[3 * j    ]);
      atomicAdd(&aggr[320 + 3 * u + 1], tt * ev[3 * j + 1]);
      atomicAdd(&aggr[320 + 3 * u + 2], tt * ev[3 * j + 2]);
    }
  }
  wgemv(wa, Wm3, h2s + tid, 3);
  #pragma unroll
  for (int uc = 0; uc < 8; ++uc) {
    float ev[24];
    ld8(ev,      yrow + 64 + uc * 24);
    ld8(ev + 8,  yrow + 64 + uc * 24 + 8);
    ld8(ev + 16, yrow + 64 + uc * 24 + 16);
    #pragma unroll
    for (int j = 0; j < 8; ++j) {
      int u = uc * 8 + j;
      float d = ev[3*j]*shv.y + ev[3*j+1]*shv.z + ev[3*j+2]*shv.w;
      atomicAdd(&aggr[64 + u], wa[u] * d * c4);
    }
  }
}

// ---------------- kernel C: node post ----------------
__global__ __launch_bounds__(256) void node_post(
    const float* __restrict__ feats, const float* __restrict__ attrs,
    const float* __restrict__ agg, const float* __restrict__ W2s,
    const float* __restrict__ W2v, const float* __restrict__ Wr_s,
    const float* __restrict__ Wr_v, float* __restrict__ out)
{
  __shared__ __align__(16) float sA[320 * 8];
  __shared__ __align__(16) float sX0[64 * 8];
  __shared__ __align__(16) float sX1[192 * 8];
  __shared__ __align__(16) float sAt[5 * 8];
  __shared__ __align__(16) float sAggS[128 * 8];
  __shared__ __align__(16) float sAggV[384 * 8];
  __shared__ __align__(16) float sZs[8 * 128];
  __shared__ __align__(16) float sZv[8 * 192];

  const int t = threadIdx.x;
  const int n0 = blockIdx.x * 8;
  const float nr = 0.05590169943749474f;
  const float n2 = 0.08838834764831845f;

  #pragma unroll
  for (int nb = 0; nb < 8; ++nb) {
    float v = feats[(size_t)(n0 + nb) * 256 + t];
    if (t < 64) sX0[t * 8 + nb] = v;
    else        sX1[(t - 64) * 8 + nb] = v;
  }
  if (t < 40) {
    int nb = t & 7, s = t >> 3;
    sAt[s * 8 + nb] = attrs[(size_t)(n0 + nb) * 5 + s] * nr;
  }
  #pragma unroll
  for (int i = 0; i < 16; ++i) {
    int idx = i * 256 + t;
    int nb = idx >> 9;
    int c = idx & 511;
    float v = agg[(size_t)(n0 + nb) * 512 + c] * n2;
    if (c < 128) sAggS[c * 8 + nb] = v;
    else         sAggV[(c - 128) * 8 + nb] = v;
  }
  __syncthreads();

  #pragma unroll
  for (int i = 0; i < 10; ++i) {
    int idx = i * 256 + t;
    int nb = idx & 7;
    int us = idx >> 3;
    int u = us / 5;
    int s = us - u * 5;
    sA[us * 8 + nb] = sX0[u * 8 + nb] * sAt[s * 8 + nb];
  }
  __syncthreads();

  float av[8][3];

  if (t < 128) {
    const int v = t;
    float acc[8];
    #pragma unroll
    for (int nb = 0; nb < 8; ++nb) acc[nb] = 0.f;
    for (int us = 0; us < 320; ++us)
      fma8(acc, &sA[us * 8], Wr_s[us * 128 + v]);
    for (int c = 0; c < 128; ++c)
      fma8(acc, &sAggS[c * 8], W2s[c * 128 + v]);
    #pragma unroll
    for (int nb = 0; nb < 8; ++nb) sZs[nb * 128 + v] = acc[nb];
  } else {
    const int tv = t - 128;
    const int v = tv & 63;
    const int half = tv >> 6;
    #pragma unroll
    for (int nb = 0; nb < 8; ++nb)
      #pragma unroll
      for (int m = 0; m < 3; ++m) av[nb][m] = 0.f;

    const int u0 = half * 32;
    for (int u = u0; u < u0 + 32; ++u) {
      float xr0[8], xr1[8], xr2[8];
      ld8(xr0, &sX1[(u * 3 + 0) * 8]);
      ld8(xr1, &sX1[(u * 3 + 1) * 8]);
      ld8(xr2, &sX1[(u * 3 + 2) * 8]);
      #pragma unroll
      for (int s = 0; s < 5; ++s) {
        float w = Wr_v[(u * 5 + s) * 64 + v];
        float at[8];
        ld8(at, &sAt[s * 8]);
        #pragma unroll
        for (int nb = 0; nb < 8; ++nb) {
          float tt = at[nb] * w;
          av[nb][0] = fmaf(xr0[nb], tt, av[nb][0]);
          av[nb][1] = fmaf(xr1[nb], tt, av[nb][1]);
          av[nb][2] = fmaf(xr2[nb], tt, av[nb][2]);
        }
      }
    }
    const int c0 = half * 64;
    for (int c = c0; c < c0 + 64; ++c) {
      float w = W2v[c * 64 + v];
      float g0[8], g1[8], g2[8];
      ld8(g0, &sAggV[(c * 3 + 0) * 8]);
      ld8(g1, &sAggV[(c * 3 + 1) * 8]);
      ld8(g2, &sAggV[(c * 3 + 2) * 8]);
      #pragma unroll
      for (int nb = 0; nb < 8; ++nb) {
        av[nb][0] = fmaf(g0[nb], w, av[nb][0]);
        av[nb][1] = fmaf(g1[nb], w, av[nb][1]);
        av[nb][2] = fmaf(g2[nb], w, av[nb][2]);
      }
    }
    if (half == 0) {
      #pragma unroll
      for (int nb = 0; nb < 8; ++nb)
        #pragma unroll
        for (int m = 0; m < 3; ++m)
          sZv[nb * 192 + v * 3 + m] = av[nb][m];
    }
  }
  __syncthreads();
  if (t >= 192) {
    const int v = (t - 128) & 63;
    #pragma unroll
    for (int nb = 0; nb < 8; ++nb)
      #pragma unroll
      for (int m = 0; m < 3; ++m)
        sZv[nb * 192 + v * 3 + m] += av[nb][m];
  }
  __syncthreads();

  const int i = t - 64;
  const int ug = (t >= 64) ? (i / 3) : 0;
  #pragma unroll
  for (int nb = 0; nb < 8; ++nb) {
    float val;
    if (t < 64) {
      val = swishf(sZs[nb * 128 + t]);
    } else {
      float gate = swishf(sZs[nb * 128 + 64 + ug]);
      val = gate * sZv[nb * 192 + i];
    }
    out[(size_t)(n0 + nb) * 256 + t] = val;
  }
}

extern "C" void kernel_launch(void* const* d_in, const int* in_sizes, int n_in,
                              void* d_out, int out_size, void* d_ws, size_t ws_size,
                              hipStream_t stream)
{
  const float* feats = (const float*)d_in[0];
  const float* attrs = (const float*)d_in[1];
  const float* esh   = (const float*)d_in[2];
  const int*   snd   = (const int*)d_in[3];
  const int*   rcv   = (const int*)d_in[4];
  const float* emb   = (const float*)d_in[5];
  const float* Wl0   = (const float*)d_in[6];
  const float* Wl1   = (const float*)d_in[7];
  const float* Wm1   = (const float*)d_in[8];
  const float* Wm2   = (const float*)d_in[9];
  const float* Wm3   = (const float*)d_in[10];
  const float* W2s   = (const float*)d_in[11];
  const float* W2v   = (const float*)d_in[12];
  const float* Wr_s  = (const float*)d_in[13];
  const float* Wr_v  = (const float*)d_in[14];
  float* out = (float*)d_out;

  float* y   = (float*)d_ws;                     // NN*256 f32
  float* agg = y + (size_t)NN * 256;             // NN*512 f32
  // CSR-build transients aliased into agg (agg written only by gather_fused):
  int* counts = (int*)agg;
  int* cursor = counts + NN;
  int* csr_edge = (int*)(agg + (size_t)NN * 512);   // NE ints
  int* offsets  = csr_edge + NE;                    // NN+1 ints
  size_t need = (size_t)((char*)(offsets + NN + 1) - (char*)d_ws);

  if (ws_size >= need) {
    hipMemsetAsync(counts, 0, (size_t)NN * sizeof(int), stream);
    hist_kernel<<<NE / 256, 256, 0, stream>>>(rcv, counts);
    scan_kernel<<<1, 1024, 0, stream>>>(counts, offsets, cursor);
    scatter_kernel<<<NE / 256, 256, 0, stream>>>(rcv, cursor, csr_edge);
    node_prep<<<NN / 4, 256, 0, stream>>>(feats, Wl0, Wl1, y);
    gather_fused<<<NN / 8, 512, 0, stream>>>(y, csr_edge, snd, esh, emb,
                                             Wm1, Wm2, Wm3, offsets, agg);
    node_post<<<NN / 8, 256, 0, stream>>>(feats, attrs, agg, W2s, W2v, Wr_s, Wr_v, out);
  } else {
    hipMemsetAsync(agg, 0, (size_t)NN * 512 * sizeof(float), stream);
    node_prep<<<NN / 4, 256, 0, stream>>>(feats, Wl0, Wl1, y);
    edge_kernel<<<NE / 256, 256, 0, stream>>>(y, esh, snd, rcv, emb, Wm1, Wm2, Wm3, agg);
    node_post<<<NN / 8, 256, 0, stream>>>(feats, attrs, agg, W2s, W2v, Wr_s, Wr_v, out);
  }
}

// Round 6
// 646.656 us; speedup vs baseline: 9.9269x; 8.4445x over previous
//
#include <hip/hip_runtime.h>

// NequIP-style layer, f32.
// Fast path (~62.8MB ws): CSR edge-permutation -> gather_fused
//   (8 nodes/block wave-per-node, batch-2 edges; Wm3 (swizzled) + Wm2 staged
//    in 80KB LDS; BOUNDED unrolls so the scheduler can't inflate live ranges
//    past the 128-VGPR cap; no atomics, no spills) -> node_post.
// Fallback path (61.4MB ws): atomic edge_kernel (round-1, known-good).

#define NN 20000
#define NE 320000

__device__ __forceinline__ float swishf(float x) {
  float t = __expf(-fabsf(x));
  float r = 1.0f / (1.0f + t);
  float sig = (x >= 0.0f) ? r : t * r;
  return x * sig;
}

__device__ __forceinline__ float rlane(float v, int k) {
  return __uint_as_float(__builtin_amdgcn_readlane(__float_as_uint(v), k));
}

__device__ __forceinline__ void ld8(float d[8], const float* p) {
  float4 a0 = *(const float4*)p;
  float4 a1 = *(const float4*)(p + 4);
  d[0]=a0.x; d[1]=a0.y; d[2]=a0.z; d[3]=a0.w;
  d[4]=a1.x; d[5]=a1.y; d[6]=a1.z; d[7]=a1.w;
}

__device__ __forceinline__ void fma8(float (&acc)[8], const float* p, float w) {
  float4 a0 = *(const float4*)p;
  float4 a1 = *(const float4*)(p + 4);
  acc[0] = fmaf(a0.x, w, acc[0]); acc[1] = fmaf(a0.y, w, acc[1]);
  acc[2] = fmaf(a0.z, w, acc[2]); acc[3] = fmaf(a0.w, w, acc[3]);
  acc[4] = fmaf(a1.x, w, acc[4]); acc[5] = fmaf(a1.y, w, acc[5]);
  acc[6] = fmaf(a1.z, w, acc[6]); acc[7] = fmaf(a1.w, w, acc[7]);
}

// ---------------- CSR build ----------------
__global__ __launch_bounds__(256) void hist_kernel(const int* __restrict__ rcv,
                                                   int* __restrict__ counts) {
  int e = blockIdx.x * 256 + threadIdx.x;
  atomicAdd(&counts[rcv[e]], 1);
}

__global__ __launch_bounds__(1024) void scan_kernel(const int* __restrict__ counts,
                                                    int* __restrict__ offsets,
                                                    int* __restrict__ cursor) {
  __shared__ int part[1024];
  const int t = threadIdx.x;
  const int base = t * 20;
  int loc[20];
  int s = 0;
  #pragma unroll
  for (int j = 0; j < 20; ++j) {
    int idx = base + j;
    int c = (idx < NN) ? counts[idx] : 0;
    loc[j] = s;
    s += c;
  }
  part[t] = s;
  __syncthreads();
  for (int d = 1; d < 1024; d <<= 1) {
    int v = (t >= d) ? part[t - d] : 0;
    __syncthreads();
    part[t] += v;
    __syncthreads();
  }
  int excl = (t > 0) ? part[t - 1] : 0;
  #pragma unroll
  for (int j = 0; j < 20; ++j) {
    int idx = base + j;
    if (idx < NN) {
      int o = excl + loc[j];
      offsets[idx] = o;
      cursor[idx] = o;
    }
  }
  if (t == 1023) offsets[NN] = part[1023];
}

__global__ __launch_bounds__(256) void scatter_kernel(
    const int* __restrict__ rcv, int* __restrict__ cursor,
    int* __restrict__ csr_edge) {
  int e = blockIdx.x * 256 + threadIdx.x;
  int r = rcv[e];
  int pos = atomicAdd(&cursor[r], 1);
  csr_edge[pos] = e;
}

// ---------------- kernel A: y = [x0@Wl0, x1@Wl1] * nl ----------------
__global__ __launch_bounds__(256) void node_prep(
    const float* __restrict__ feats, const float* __restrict__ Wl0,
    const float* __restrict__ Wl1, float* __restrict__ y)
{
  __shared__ __align__(16) float sX[4 * 256];
  const int t = threadIdx.x;
  const int n0 = blockIdx.x * 4;
  #pragma unroll
  for (int nb = 0; nb < 4; ++nb)
    sX[nb * 256 + t] = feats[(size_t)(n0 + nb) * 256 + t];
  __syncthreads();

  float acc[4] = {0.f, 0.f, 0.f, 0.f};
  if (t < 64) {
    const int v = t;
    for (int u = 0; u < 64; ++u) {
      float w = Wl0[u * 64 + v];
      acc[0] = fmaf(sX[0 * 256 + u], w, acc[0]);
      acc[1] = fmaf(sX[1 * 256 + u], w, acc[1]);
      acc[2] = fmaf(sX[2 * 256 + u], w, acc[2]);
      acc[3] = fmaf(sX[3 * 256 + u], w, acc[3]);
    }
  } else {
    const int i = t - 64;
    const int v = i / 3;
    const int m = i - v * 3;
    for (int u = 0; u < 64; ++u) {
      float w = Wl1[u * 64 + v];
      int xi = 64 + u * 3 + m;
      acc[0] = fmaf(sX[0 * 256 + xi], w, acc[0]);
      acc[1] = fmaf(sX[1 * 256 + xi], w, acc[1]);
      acc[2] = fmaf(sX[2 * 256 + xi], w, acc[2]);
      acc[3] = fmaf(sX[3 * 256 + xi], w, acc[3]);
    }
  }
  #pragma unroll
  for (int nb = 0; nb < 4; ++nb)
    y[(size_t)(n0 + nb) * 256 + t] = acc[nb] * 0.125f;   // nl = 1/sqrt(64)
}

// ---------------- fused gather v4 ----------------
// 8 nodes/block (512 thr), wave-per-node, batch-2 edges.
// Wm3^T swizzled + Wm2 staged in LDS (80KB total, 2 blocks/CU).
// Unrolls BOUNDED (8 / 2) so hoisted-load live ranges stay under the
// 128-VGPR cap -- round-4/5 spills came from full-unroll hoisting.
__global__ __launch_bounds__(512, 2) void gather_fused(
    const float* __restrict__ y, const int* __restrict__ csr_edge,
    const int* __restrict__ snd, const float* __restrict__ esh,
    const float* __restrict__ emb, const float* __restrict__ Wm1,
    const float* __restrict__ Wm2, const float* __restrict__ Wm3,
    const int* __restrict__ offsets, float* __restrict__ agg)
{
  __shared__ __align__(16) float sW3[64 * 256];   // 64KB, transposed+swizzled
  __shared__ __align__(16) float sW2[64 * 64];    // 16KB, [k][l] natural
  const int t = threadIdx.x;

  // stage Wm3 (k-major [64][256]) -> sW3 transposed+swizzled
  #pragma unroll 4
  for (int i = 0; i < 32; ++i) {
    int idx = i * 512 + t;          // 0..16383
    int k = idx >> 8;               // 0..63
    int c = idx & 255;              // output dim 0..255
    float v = Wm3[idx];
    int kg = k >> 2, kk = k & 3;
    sW3[c * 64 + (((kg ^ (c & 15)) & 15) << 2) + kk] = v;
  }
  // stage Wm2 verbatim
  #pragma unroll
  for (int i = 0; i < 8; ++i)
    sW2[i * 512 + t] = Wm2[i * 512 + t];
  __syncthreads();

  const int l = t & 63;
  const int wv = t >> 6;
  const int n = blockIdx.x * 8 + wv;
  const int row0 = offsets[n];
  const int row1 = offsets[n + 1];

  // hoist Wm1 column l (8 persistent regs)
  float wm1r[8];
  #pragma unroll
  for (int j = 0; j < 8; ++j) wm1r[j] = Wm1[j * 64 + l];

  float s0 = 0.f, s1 = 0.f;
  float v0x = 0.f, v0y = 0.f, v0z = 0.f;
  float v1x = 0.f, v1y = 0.f, v1z = 0.f;

  const int swz = ((l & 15) << 2);   // row-dependent part of the XOR swizzle

  for (int i = row0; i < row1; i += 2) {
    const int nb = row1 - i;

    int   sn[2];
    float4 sh[2];
    float h1[2];
    #pragma unroll
    for (int b = 0; b < 2; ++b) {
      int idx = (b < nb) ? (i + b) : i;      // duplicate edge 0 if inactive
      int e = csr_edge[idx];
      sn[b] = snd[e];
      float4 s = *(const float4*)(esh + (size_t)e * 4);
      if (b >= nb) s = make_float4(0.f, 0.f, 0.f, 0.f);  // every TP term has sh
      sh[b] = s;
      float em8[8];
      ld8(em8, emb + (size_t)e * 8);
      float a = 0.f;
      #pragma unroll
      for (int j = 0; j < 8; ++j) a = fmaf(em8[j], wm1r[j], a);
      h1[b] = swishf(a * 0.35355339059327373f);    // /sqrt(8)
    }

    // ---- h2[l] = swish( (sum_k h1[k]*Wm2[k][l]) / 8 ); Wm2 from LDS ----
    float h2[2] = {0.f, 0.f};
    #pragma unroll 8
    for (int k = 0; k < 64; ++k) {
      float wv2 = sW2[k * 64 + l];
      h2[0] = fmaf(rlane(h1[0], k), wv2, h2[0]);
      h2[1] = fmaf(rlane(h1[1], k), wv2, h2[1]);
    }
    h2[0] = swishf(h2[0] * 0.125f);
    h2[1] = swishf(h2[1] * 0.125f);

    // ---- w[p*64+l] = sum_k h2[k]*Wm3[k][p*64+l] via LDS b128 reads ----
    // unroll 2: at most 8 live float4 loads -> no register blow-up.
    float w0[2] = {0,0}, w1a[2] = {0,0}, w2a[2] = {0,0}, w3a[2] = {0,0};
    #pragma unroll 2
    for (int g = 0; g < 16; ++g) {
      int sbase = l * 64 + (((g << 2) ^ swz) & 63);   // ((g^(l&15))<<2)
      float4 m0 = *(const float4*)&sW3[sbase];
      float4 m1 = *(const float4*)&sW3[sbase + 4096];
      float4 m2 = *(const float4*)&sW3[sbase + 8192];
      float4 m3 = *(const float4*)&sW3[sbase + 12288];
      #pragma unroll
      for (int kk = 0; kk < 4; ++kk) {
        const int k = 4 * g + kk;
        #pragma unroll
        for (int b = 0; b < 2; ++b) {
          float bc = rlane(h2[b], k);
          w0[b]  = fmaf(bc, (&m0.x)[kk], w0[b]);
          w1a[b] = fmaf(bc, (&m1.x)[kk], w1a[b]);
          w2a[b] = fmaf(bc, (&m2.x)[kk], w2a[b]);
          w3a[b] = fmaf(bc, (&m3.x)[kk], w3a[b]);
        }
      }
    }

    // ---- tensor product + accumulate ----
    #pragma unroll
    for (int b = 0; b < 2; ++b) {
      const float* yr = y + (size_t)sn[b] * 256;
      float e0 = yr[l];
      float ex = yr[64 + 3 * l], ey = yr[65 + 3 * l], ez = yr[66 + 3 * l];
      float4 s = sh[b];
      s0 = fmaf(w0[b] * e0, s.x, s0);
      s1 = fmaf(w3a[b], fmaf(ex, s.y, fmaf(ey, s.z, ez * s.w)), s1);
      float t2 = w1a[b] * e0;
      v0x = fmaf(t2, s.y, v0x); v0y = fmaf(t2, s.z, v0y); v0z = fmaf(t2, s.w, v0z);
      float t3 = w2a[b] * s.x;
      v1x = fmaf(t3, ex, v1x); v1y = fmaf(t3, ey, v1y); v1z = fmaf(t3, ez, v1z);
    }
  }

  const float SCL = 0.0078125f;                          // (1/8 w-scale) / 16
  const float C4  = 0.125f / (16.0f * 1.7320508075688772f);
  float* ar = agg + (size_t)n * 512;
  ar[l]       = s0 * SCL;
  ar[64 + l]  = s1 * C4;
  ar[128 + 3 * l]     = v0x * SCL;
  ar[128 + 3 * l + 1] = v0y * SCL;
  ar[128 + 3 * l + 2] = v0z * SCL;
  ar[320 + 3 * l]     = v1x * SCL;
  ar[320 + 3 * l + 1] = v1y * SCL;
  ar[320 + 3 * l + 2] = v1z * SCL;
}

// GEMV helper (fallback path)
__device__ __forceinline__ void wgemv(float (&wa)[64], const float* __restrict__ Wm3,
                                      const float* h2col, int p)
{
  #pragma unroll
  for (int v = 0; v < 64; ++v) wa[v] = 0.f;
  #pragma unroll 2
  for (int k = 0; k < 64; ++k) {
    float h2k = h2col[k * 256];
    const float* wrow = Wm3 + k * 256 + p * 64;
    #pragma unroll
    for (int v = 0; v < 64; ++v) wa[v] = fmaf(h2k, wrow[v], wa[v]);
  }
}

// ---------------- fallback: atomic edge kernel (round-1, known-good) ----------------
__global__ __launch_bounds__(256) void edge_kernel(
    const float* __restrict__ y, const float* __restrict__ edge_sh,
    const int* __restrict__ senders, const int* __restrict__ receivers,
    const float* __restrict__ emb, const float* __restrict__ Wm1,
    const float* __restrict__ Wm2, const float* __restrict__ Wm3,
    float* __restrict__ agg)
{
  __shared__ float h2s[64 * 256];
  const int tid = threadIdx.x;
  const int e = blockIdx.x * 256 + tid;
  const int s = senders[e];
  const int r = receivers[e];
  const float4 shv = *(const float4*)(edge_sh + (size_t)e * 4);
  float e8[8];
  ld8(e8, emb + (size_t)e * 8);

  float h2a[64];
  #pragma unroll
  for (int v = 0; v < 64; ++v) h2a[v] = 0.f;
  #pragma unroll 2
  for (int k = 0; k < 64; ++k) {
    float a = 0.f;
    #pragma unroll
    for (int j = 0; j < 8; ++j) a = fmaf(e8[j], Wm1[j * 64 + k], a);
    float h1k = swishf(a * 0.35355339059327373f);
    const float* wrow = Wm2 + k * 64;
    #pragma unroll
    for (int v = 0; v < 64; ++v) h2a[v] = fmaf(h1k, wrow[v], h2a[v]);
  }
  #pragma unroll
  for (int v = 0; v < 64; ++v)
    h2s[v * 256 + tid] = swishf(h2a[v] * 0.125f);

  const float* yrow = y + (size_t)s * 256;
  float* aggr = agg + (size_t)r * 512;
  const float SCL = 0.0078125f;
  const float c0  = shv.x * SCL;
  const float c1x = shv.y * SCL, c1y = shv.z * SCL, c1z = shv.w * SCL;
  const float c4  = 0.125f / (16.0f * 1.7320508075688772f);

  float wa[64];

  wgemv(wa, Wm3, h2s + tid, 0);
  #pragma unroll
  for (int uc = 0; uc < 8; ++uc) {
    float ev[8];
    ld8(ev, yrow + uc * 8);
    #pragma unroll
    for (int j = 0; j < 8; ++j) {
      int u = uc * 8 + j;
      atomicAdd(&aggr[u], wa[u] * ev[j] * c0);
    }
  }
  wgemv(wa, Wm3, h2s + tid, 1);
  #pragma unroll
  for (int uc = 0; uc < 8; ++uc) {
    float ev[8];
    ld8(ev, yrow + uc * 8);
    #pragma unroll
    for (int j = 0; j < 8; ++j) {
      int u = uc * 8 + j;
      float tt = wa[u] * ev[j];
      atomicAdd(&aggr[128 + 3 * u    ], tt * c1x);
      atomicAdd(&aggr[128 + 3 * u + 1], tt * c1y);
      atomicAdd(&aggr[128 + 3 * u + 2], tt * c1z);
    }
  }
  wgemv(wa, Wm3, h2s + tid, 2);
  #pragma unroll
  for (int uc = 0; uc < 8; ++uc) {
    float ev[24];
    ld8(ev,      yrow + 64 + uc * 24);
    ld8(ev + 8,  yrow + 64 + uc * 24 + 8);
    ld8(ev + 16, yrow + 64 + uc * 24 + 16);
    #pragma unroll
    for (int j = 0; j < 8; ++j) {
      int u = uc * 8 + j;
      float tt = wa[u] * c0;
      atomicAdd(&aggr[320 + 3 * u    ], tt * ev[3 * j    ]);
      atomicAdd(&aggr[320 + 3 * u + 1], tt * ev[3 * j + 1]);
      atomicAdd(&aggr[320 + 3 * u + 2], tt * ev[3 * j + 2]);
    }
  }
  wgemv(wa, Wm3, h2s + tid, 3);
  #pragma unroll
  for (int uc = 0; uc < 8; ++uc) {
    float ev[24];
    ld8(ev,      yrow + 64 + uc * 24);
    ld8(ev + 8,  yrow + 64 + uc * 24 + 8);
    ld8(ev + 16, yrow + 64 + uc * 24 + 16);
    #pragma unroll
    for (int j = 0; j < 8; ++j) {
      int u = uc * 8 + j;
      float d = ev[3*j]*shv.y + ev[3*j+1]*shv.z + ev[3*j+2]*shv.w;
      atomicAdd(&aggr[64 + u], wa[u] * d * c4);
    }
  }
}

// ---------------- kernel C: node post ----------------
__global__ __launch_bounds__(256) void node_post(
    const float* __restrict__ feats, const float* __restrict__ attrs,
    const float* __restrict__ agg, const float* __restrict__ W2s,
    const float* __restrict__ W2v, const float* __restrict__ Wr_s,
    const float* __restrict__ Wr_v, float* __restrict__ out)
{
  __shared__ __align__(16) float sA[320 * 8];
  __shared__ __align__(16) float sX0[64 * 8];
  __shared__ __align__(16) float sX1[192 * 8];
  __shared__ __align__(16) float sAt[5 * 8];
  __shared__ __align__(16) float sAggS[128 * 8];
  __shared__ __align__(16) float sAggV[384 * 8];
  __shared__ __align__(16) float sZs[8 * 128];
  __shared__ __align__(16) float sZv[8 * 192];

  const int t = threadIdx.x;
  const int n0 = blockIdx.x * 8;
  const float nr = 0.05590169943749474f;
  const float n2 = 0.08838834764831845f;

  #pragma unroll
  for (int nb = 0; nb < 8; ++nb) {
    float v = feats[(size_t)(n0 + nb) * 256 + t];
    if (t < 64) sX0[t * 8 + nb] = v;
    else        sX1[(t - 64) * 8 + nb] = v;
  }
  if (t < 40) {
    int nb = t & 7, s = t >> 3;
    sAt[s * 8 + nb] = attrs[(size_t)(n0 + nb) * 5 + s] * nr;
  }
  #pragma unroll
  for (int i = 0; i < 16; ++i) {
    int idx = i * 256 + t;
    int nb = idx >> 9;
    int c = idx & 511;
    float v = agg[(size_t)(n0 + nb) * 512 + c] * n2;
    if (c < 128) sAggS[c * 8 + nb] = v;
    else         sAggV[(c - 128) * 8 + nb] = v;
  }
  __syncthreads();

  #pragma unroll
  for (int i = 0; i < 10; ++i) {
    int idx = i * 256 + t;
    int nb = idx & 7;
    int us = idx >> 3;
    int u = us / 5;
    int s = us - u * 5;
    sA[us * 8 + nb] = sX0[u * 8 + nb] * sAt[s * 8 + nb];
  }
  __syncthreads();

  float av[8][3];

  if (t < 128) {
    const int v = t;
    float acc[8];
    #pragma unroll
    for (int nb = 0; nb < 8; ++nb) acc[nb] = 0.f;
    for (int us = 0; us < 320; ++us)
      fma8(acc, &sA[us * 8], Wr_s[us * 128 + v]);
    for (int c = 0; c < 128; ++c)
      fma8(acc, &sAggS[c * 8], W2s[c * 128 + v]);
    #pragma unroll
    for (int nb = 0; nb < 8; ++nb) sZs[nb * 128 + v] = acc[nb];
  } else {
    const int tv = t - 128;
    const int v = tv & 63;
    const int half = tv >> 6;
    #pragma unroll
    for (int nb = 0; nb < 8; ++nb)
      #pragma unroll
      for (int m = 0; m < 3; ++m) av[nb][m] = 0.f;

    const int u0 = half * 32;
    for (int u = u0; u < u0 + 32; ++u) {
      float xr0[8], xr1[8], xr2[8];
      ld8(xr0, &sX1[(u * 3 + 0) * 8]);
      ld8(xr1, &sX1[(u * 3 + 1) * 8]);
      ld8(xr2, &sX1[(u * 3 + 2) * 8]);
      #pragma unroll
      for (int s = 0; s < 5; ++s) {
        float w = Wr_v[(u * 5 + s) * 64 + v];
        float at[8];
        ld8(at, &sAt[s * 8]);
        #pragma unroll
        for (int nb = 0; nb < 8; ++nb) {
          float tt = at[nb] * w;
          av[nb][0] = fmaf(xr0[nb], tt, av[nb][0]);
          av[nb][1] = fmaf(xr1[nb], tt, av[nb][1]);
          av[nb][2] = fmaf(xr2[nb], tt, av[nb][2]);
        }
      }
    }
    const int c0 = half * 64;
    for (int c = c0; c < c0 + 64; ++c) {
      float w = W2v[c * 64 + v];
      float g0[8], g1[8], g2[8];
      ld8(g0, &sAggV[(c * 3 + 0) * 8]);
      ld8(g1, &sAggV[(c * 3 + 1) * 8]);
      ld8(g2, &sAggV[(c * 3 + 2) * 8]);
      #pragma unroll
      for (int nb = 0; nb < 8; ++nb) {
        av[nb][0] = fmaf(g0[nb], w, av[nb][0]);
        av[nb][1] = fmaf(g1[nb], w, av[nb][1]);
        av[nb][2] = fmaf(g2[nb], w, av[nb][2]);
      }
    }
    if (half == 0) {
      #pragma unroll
      for (int nb = 0; nb < 8; ++nb)
        #pragma unroll
        for (int m = 0; m < 3; ++m)
          sZv[nb * 192 + v * 3 + m] = av[nb][m];
    }
  }
  __syncthreads();
  if (t >= 192) {
    const int v = (t - 128) & 63;
    #pragma unroll
    for (int nb = 0; nb < 8; ++nb)
      #pragma unroll
      for (int m = 0; m < 3; ++m)
        sZv[nb * 192 + v * 3 + m] += av[nb][m];
  }
  __syncthreads();

  const int i = t - 64;
  const int ug = (t >= 64) ? (i / 3) : 0;
  #pragma unroll
  for (int nb = 0; nb < 8; ++nb) {
    float val;
    if (t < 64) {
      val = swishf(sZs[nb * 128 + t]);
    } else {
      float gate = swishf(sZs[nb * 128 + 64 + ug]);
      val = gate * sZv[nb * 192 + i];
    }
    out[(size_t)(n0 + nb) * 256 + t] = val;
  }
}

extern "C" void kernel_launch(void* const* d_in, const int* in_sizes, int n_in,
                              void* d_out, int out_size, void* d_ws, size_t ws_size,
                              hipStream_t stream)
{
  const float* feats = (const float*)d_in[0];
  const float* attrs = (const float*)d_in[1];
  const float* esh   = (const float*)d_in[2];
  const int*   snd   = (const int*)d_in[3];
  const int*   rcv   = (const int*)d_in[4];
  const float* emb   = (const float*)d_in[5];
  const float* Wl0   = (const float*)d_in[6];
  const float* Wl1   = (const float*)d_in[7];
  const float* Wm1   = (const float*)d_in[8];
  const float* Wm2   = (const float*)d_in[9];
  const float* Wm3   = (const float*)d_in[10];
  const float* W2s   = (const float*)d_in[11];
  const float* W2v   = (const float*)d_in[12];
  const float* Wr_s  = (const float*)d_in[13];
  const float* Wr_v  = (const float*)d_in[14];
  float* out = (float*)d_out;

  float* y   = (float*)d_ws;                     // NN*256 f32
  float* agg = y + (size_t)NN * 256;             // NN*512 f32
  // CSR-build transients aliased into agg (agg written only by gather_fused):
  int* counts = (int*)agg;
  int* cursor = counts + NN;
  int* csr_edge = (int*)(agg + (size_t)NN * 512);   // NE ints
  int* offsets  = csr_edge + NE;                    // NN+1 ints
  size_t need = (size_t)((char*)(offsets + NN + 1) - (char*)d_ws);

  if (ws_size >= need) {
    hipMemsetAsync(counts, 0, (size_t)NN * sizeof(int), stream);
    hist_kernel<<<NE / 256, 256, 0, stream>>>(rcv, counts);
    scan_kernel<<<1, 1024, 0, stream>>>(counts, offsets, cursor);
    scatter_kernel<<<NE / 256, 256, 0, stream>>>(rcv, cursor, csr_edge);
    node_prep<<<NN / 4, 256, 0, stream>>>(feats, Wl0, Wl1, y);
    gather_fused<<<NN / 8, 512, 0, stream>>>(y, csr_edge, snd, esh, emb,
                                             Wm1, Wm2, Wm3, offsets, agg);
    node_post<<<NN / 8, 256, 0, stream>>>(feats, attrs, agg, W2s, W2v, Wr_s, Wr_v, out);
  } else {
    hipMemsetAsync(agg, 0, (size_t)NN * 512 * sizeof(float), stream);
    node_prep<<<NN / 4, 256, 0, stream>>>(feats, Wl0, Wl1, y);
    edge_kernel<<<NE / 256, 256, 0, stream>>>(y, esh, snd, rcv, emb, Wm1, Wm2, Wm3, agg);
    node_post<<<NN / 8, 256, 0, stream>>>(feats, attrs, agg, W2s, W2v, Wr_s, Wr_v, out);
  }
}